// Round 1
// baseline (3282.476 us; speedup 1.0000x reference)
//
#include <hip/hip_runtime.h>
#include <hip/hip_bf16.h>

// Problem constants (from reference)
#define HH 512
#define WW 512
#define NN 8192
#define FF 2
#define BB 8
#define MM (NN * FF)      // 16384 splats per batch
#define HW (HH * WW)      // 262144 pixels per batch image

// Strip binning: exclusive 8-row strips, one block owns one strip in LDS.
#define SHLOG 3
#define SH 8                  // strip height (rows)
#define SPI (HH / SH)         // 64 strips per image
#define BINS (BB * SPI)       // 512 bins
#define NBLK 128              // blocks for count/fill (1024 thr each -> exact cover)
#define BLKS_PER_B (NBLK / BB)   // 16
#define LIST_CAP (BB * MM * 8)   // max 7 strips/record (Rf<=20.5 -> <=42 rows)

// ---- dual-dtype input load: f32mode ? float : bf16 ----
__device__ __forceinline__ float ld(const void* p, int i, int f32mode) {
  if (f32mode) return ((const float*)p)[i];
  unsigned u = ((const unsigned short*)p)[i];
  return __uint_as_float(u << 16);
}

// Abramowitz & Stegun 7.1.26, |err| <= 1.5e-7.
__device__ __forceinline__ float erf_f(float x) {
  float ax = fabsf(x);
  float t = 1.0f / (1.0f + 0.3275911f * ax);
  float y = t * (0.254829592f +
           t * (-0.284496736f +
           t * (1.421413741f +
           t * (-1.453152027f +
           t * 1.061405429f))));
  y = 1.0f - y * __expf(-ax * ax);
  return copysignf(y, x);
}

// Strip range touched by a record: gaussian window (5s truncation, matches
// the scatter) unioned with the bubble's 2 bilinear rows (f=0 records only).
__device__ __forceinline__ void strip_range(float row, float s, int has_bubble,
                                            int& slo, int& shi) {
  float Rf = 5.0f * s + 0.5f;
  int rlo = max(0, (int)ceilf(row - Rf));
  int rhi = min(HH - 1, (int)floorf(row + Rf));
  slo = 1; shi = 0;                       // empty
  if (rlo <= rhi) { slo = rlo >> SHLOG; shi = rhi >> SHLOG; }
  if (has_bubble) {
    int r0 = (int)floorf(row);
    int rr0 = min(max(r0, 0), HH - 1);
    int rr1 = min(max(r0 + 1, 0), HH - 1);
    int b0 = rr0 >> SHLOG, b1 = rr1 >> SHLOG;
    if (slo > shi) { slo = b0; shi = b1; }
    else { slo = min(slo, b0); shi = max(shi, b1); }
  }
}

// K1: detect dtype, then invert the 8 4x4 transforms (Gauss-Jordan), f32.
__global__ void k_inv(const void* __restrict__ T, float* __restrict__ invT,
                      int* __restrict__ flag) {
  int b = threadIdx.x;
  if (b >= BB) return;
  const float* Tf = (const float*)T;
  int f32mode = (fabsf(Tf[0] - 1.f) < 0.4f &&
                 fabsf(Tf[5] - 1.f) < 0.4f &&
                 fabsf(Tf[10] - 1.f) < 0.4f) ? 1 : 0;
  if (b == 0) *flag = f32mode;

  float a[4][8];
  for (int r = 0; r < 4; ++r)
    for (int c = 0; c < 4; ++c) {
      a[r][c] = ld(T, b * 16 + r * 4 + c, f32mode);
      a[r][4 + c] = (r == c) ? 1.0f : 0.0f;
    }
  for (int k = 0; k < 4; ++k) {
    int p = k; float best = fabsf(a[k][k]);
    for (int i = k + 1; i < 4; ++i) {
      float v = fabsf(a[i][k]);
      if (v > best) { best = v; p = i; }
    }
    if (p != k)
      for (int c = 0; c < 8; ++c) { float tmp = a[k][c]; a[k][c] = a[p][c]; a[p][c] = tmp; }
    float inv = 1.0f / a[k][k];
    for (int c = 0; c < 8; ++c) a[k][c] *= inv;
    for (int i = 0; i < 4; ++i) {
      if (i == k) continue;
      float f = a[i][k];
      for (int c = 0; c < 8; ++c) a[i][c] -= f * a[k][c];
    }
  }
  for (int r = 0; r < 4; ++r)
    for (int c = 0; c < 4; ++c)
      invT[b * 16 + r * 4 + c] = a[r][4 + c];
}

// K2: build per-(b,m) splat records {row, col, scale, weight} and per-block
// per-strip counts (LDS-privatized; one block covers 1024 consecutive records
// of a single batch b, so only SPI strip counters are needed).
__global__ void __launch_bounds__(1024)
k_count(const void* __restrict__ centers, const void* __restrict__ scales,
        const void* __restrict__ weights, const float* __restrict__ invT,
        const int* __restrict__ flag, float4* __restrict__ table,
        int* __restrict__ blkcnt) {
  __shared__ int cnt[SPI];
  int tid = threadIdx.x;
  if (tid < SPI) cnt[tid] = 0;
  __syncthreads();

  int idx = blockIdx.x * blockDim.x + tid;   // exact cover of [0, BB*MM)
  int f32mode = *flag;
  int b = idx >> 14;           // MM = 2^14
  int m = idx & (MM - 1);
  int n = m >> 1;              // FF = 2
  const float* Tb = invT + b * 16;
  float cx = ld(centers, 3 * n, f32mode);
  float cy = ld(centers, 3 * n + 1, f32mode);
  float cz = ld(centers, 3 * n + 2, f32mode);
  float p0 = Tb[0]  * cx + Tb[1]  * cy + Tb[2]  * cz + Tb[3];
  float p1 = Tb[4]  * cx + Tb[5]  * cy + Tb[6]  * cz + Tb[7];
  float p3 = Tb[12] * cx + Tb[13] * cy + Tb[14] * cz + Tb[15];
  float inv = 1.0f / p3;
  float4 rec;
  rec.x = p0 * inv;            // row coordinate (A2P = 1)
  rec.y = p1 * inv;            // col coordinate
  rec.z = ld(scales, m, f32mode);
  rec.w = ld(weights, m, f32mode);
  table[idx] = rec;

  int slo, shi;
  strip_range(rec.x, rec.z, (idx & 1) == 0, slo, shi);
  for (int s2 = slo; s2 <= shi; ++s2) atomicAdd(&cnt[s2], 1);
  __syncthreads();
  if (tid < SPI) blkcnt[blockIdx.x * SPI + tid] = cnt[tid];
}

// K3: turn per-block counts into absolute fill bases (in-place) and bin
// offsets. One block, one thread per bin.
__global__ void k_scan(int* __restrict__ blkcnt, int* __restrict__ binoff) {
  __shared__ int tot[BINS];
  int tid = threadIdx.x;               // == bin
  int b = tid >> 6, s2 = tid & (SPI - 1);
  int acc = 0;
  for (int j = 0; j < BLKS_PER_B; ++j) {
    int idx = (b * BLKS_PER_B + j) * SPI + s2;
    int c = blkcnt[idx];
    blkcnt[idx] = acc;                 // local prefix within bin
    acc += c;
  }
  tot[tid] = acc;
  __syncthreads();
  for (int d = 1; d < BINS; d <<= 1) {
    int v = (tid >= d) ? tot[tid - d] : 0;
    __syncthreads();
    tot[tid] += v;
    __syncthreads();
  }
  int off = tot[tid] - acc;            // exclusive prefix over bins
  binoff[tid] = off;
  if (tid == BINS - 1) binoff[BINS] = tot[tid];
  for (int j = 0; j < BLKS_PER_B; ++j)
    blkcnt[(b * BLKS_PER_B + j) * SPI + s2] += off;
}

// K4: scatter record indices into per-bin lists (LDS cursors seeded from the
// per-block bases; order within a bin is irrelevant).
__global__ void __launch_bounds__(1024)
k_fill(const float4* __restrict__ table, const int* __restrict__ blkbase,
       int* __restrict__ list) {
  __shared__ int cur[SPI];
  int tid = threadIdx.x;
  if (tid < SPI) cur[tid] = blkbase[blockIdx.x * SPI + tid];
  __syncthreads();
  int idx = blockIdx.x * blockDim.x + tid;
  float4 rec = table[idx];
  int slo, shi;
  strip_range(rec.x, rec.z, (idx & 1) == 0, slo, shi);
  for (int s2 = slo; s2 <= shi; ++s2) {
    int pos = atomicAdd(&cur[s2], 1);
    list[pos] = idx;
  }
}

// K5: one block per (b,strip) bin. Accumulate all overlapping splats into an
// exclusive LDS strip (ds_add_f32 — zero global atomics), then flush straight
// to the output in the detected dtype. 16 waves/block, waves stride the list.
__global__ void __launch_bounds__(1024)
k_gather(const float4* __restrict__ table, const int* __restrict__ list,
         const int* __restrict__ binoff, const void* __restrict__ bwv,
         const int* __restrict__ flag, void* __restrict__ out) {
  __shared__ __align__(16) float tile[SH][WW];   // 16 KB
  int bin = blockIdx.x;
  int b = bin >> 6;
  int strip = bin & (SPI - 1);
  int row0 = strip << SHLOG;
  int tid = threadIdx.x;
  for (int j = tid; j < SH * WW; j += blockDim.x) ((float*)tile)[j] = 0.f;
  __syncthreads();

  int lo = binoff[bin], hi = binoff[bin + 1];
  int lane = tid & 63;
  int wv = tid >> 6;
  int nwv = blockDim.x >> 6;
  int f32mode = *flag;

  for (int p = lo + wv; p < hi; p += nwv) {
    int i = list[p];
    float4 rec = table[i];
    float row = rec.x, col = rec.y, s = rec.z, w = rec.w;

    // ---- bubble point-mass (f=0 records; each pixel owned by its strip) ----
    if ((i & 1) == 0) {
      float r0f = floorf(row), c0f = floorf(col);
      float fr = row - r0f, fc = col - c0f;
      int r0 = (int)r0f, c0 = (int)c0f;
      int rr0 = min(max(r0, 0), HH - 1), rr1 = min(max(r0 + 1, 0), HH - 1);
      int cc0 = min(max(c0, 0), WW - 1), cc1 = min(max(c0 + 1, 0), WW - 1);
      int rsel = (lane < 2) ? rr0 : rr1;
      int csel = (lane & 1) ? cc1 : cc0;
      float wr = (lane < 2) ? (1.f - fr) : fr;
      float wc = (lane & 1) ? fc : (1.f - fc);
      if (lane < 4 && (rsel >> SHLOG) == strip) {
        int n = (i & (MM - 1)) >> 1;
        float bw = ld(bwv, n, f32mode);
        atomicAdd(&tile[rsel - row0][csel], bw * wr * wc);
      }
    }

    // ---- separable gaussian, rows intersected with this strip ----
    float rs = 0.70710678118f / s;           // 1/(s*sqrt(2))
    float Rf = 5.0f * s + 0.5f;
    int rlo = max(0, (int)ceilf(row - Rf));
    int rhi = min(HH - 1, (int)floorf(row + Rf));
    int clo = max(0, (int)ceilf(col - Rf));
    int chi = min(WW - 1, (int)floorf(col + Rf));
    int srlo = max(rlo, row0);
    int srhi = min(rhi, row0 + SH - 1);
    if (srlo > srhi || clo > chi) continue;
    int nc = chi - clo + 1;
    int nrs = srhi - srlo + 1;
    // column boundary erfs, lane l holds E at x = clo+l-0.5  (nc <= 42)
    float Ew = erf_f(((float)(clo + lane) - 0.5f - col) * rs);
    float pwq = (__shfl_down(Ew, 1) - Ew) * (0.25f * w);
    // row boundary erfs within strip (<= SH+1 = 9 boundaries)
    float Eh = erf_f(((float)(srlo + lane) - 0.5f - row) * rs);
    float Dh = __shfl_down(Eh, 1) - Eh;
#pragma unroll
    for (int k = 0; k < SH; ++k) {
      if (k < nrs) {
        float dh = __shfl(Dh, k);
        if (lane < nc)
          atomicAdd(&tile[srlo - row0 + k][clo + lane], dh * pwq);
      }
    }
  }
  __syncthreads();

  // ---- exclusive flush: strip -> output (no staging image, no k_final) ----
  size_t pixbase = (size_t)b * HW + (size_t)row0 * WW;
  const float4* t4 = (const float4*)tile;
  if (f32mode) {
    float4* o = (float4*)out + (pixbase >> 2);
    for (int j = tid; j < SH * WW / 4; j += blockDim.x) o[j] = t4[j];
  } else {
    ushort4* o = (ushort4*)out + (pixbase >> 2);
    for (int j = tid; j < SH * WW / 4; j += blockDim.x) {
      float4 v = t4[j];
      __hip_bfloat16 h0 = __float2bfloat16(v.x);
      __hip_bfloat16 h1 = __float2bfloat16(v.y);
      __hip_bfloat16 h2 = __float2bfloat16(v.z);
      __hip_bfloat16 h3 = __float2bfloat16(v.w);
      ushort4 t;
      t.x = *reinterpret_cast<unsigned short*>(&h0);
      t.y = *reinterpret_cast<unsigned short*>(&h1);
      t.z = *reinterpret_cast<unsigned short*>(&h2);
      t.w = *reinterpret_cast<unsigned short*>(&h3);
      o[j] = t;
    }
  }
}

extern "C" void kernel_launch(void* const* d_in, const int* in_sizes, int n_in,
                              void* d_out, int out_size, void* d_ws, size_t ws_size,
                              hipStream_t stream) {
  const void* T       = d_in[0];   // (B,4,4)
  const void* centers = d_in[1];   // (N,3)
  const void* scales  = d_in[2];   // (N,F)
  const void* weights = d_in[3];   // (N,F)
  const void* bubble  = d_in[4];   // (N,)

  char* ws = (char*)d_ws;
  size_t off = 0;
  float4* table = (float4*)(ws + off); off += (size_t)BB * MM * 16;       // 2 MB
  int*    list  = (int*)(ws + off);    off += (size_t)LIST_CAP * 4;       // 4 MB
  int*    blkcnt= (int*)(ws + off);    off += (size_t)NBLK * SPI * 4;     // 32 KB
  int*    binoff= (int*)(ws + off);    off += (size_t)(BINS + 1) * 4 + 12;
  off = (off + 15) & ~(size_t)15;
  float*  invT  = (float*)(ws + off);  off += (size_t)BB * 16 * 4;        // 512 B
  int*    flag  = (int*)(ws + off);

  k_inv  <<<1,    64,   0, stream>>>(T, invT, flag);
  k_count<<<NBLK, 1024, 0, stream>>>(centers, scales, weights, invT, flag, table, blkcnt);
  k_scan <<<1,    BINS, 0, stream>>>(blkcnt, binoff);
  k_fill <<<NBLK, 1024, 0, stream>>>(table, blkcnt, list);
  k_gather<<<BINS,1024, 0, stream>>>(table, list, binoff, bubble, flag, d_out);
}

// Round 2
// 3279.069 us; speedup vs baseline: 1.0010x; 1.0010x over previous
//
#include <hip/hip_runtime.h>
#include <hip/hip_bf16.h>

// Problem constants (from reference)
#define HH 512
#define WW 512
#define NN 8192
#define FF 2
#define BB 8
#define MM (NN * FF)      // 16384 splats per batch
#define HW (HH * WW)      // 262144 pixels per batch image

// Strip binning: exclusive 8-row strips, one block owns one strip in LDS.
#define SHLOG 3
#define SH 8                  // strip height (rows)
#define SPI (HH / SH)         // 64 strips per image
#define BINS (BB * SPI)       // 512 bins
#define NBLK 128              // blocks for count/fill (1024 thr each -> exact cover)
#define BLKS_PER_B (NBLK / BB)   // 16
#define LIST_CAP (BB * MM * 8)   // max 7 strips/record (Rf<=20.5 -> <=42 rows)

// Native HW fp32 LDS atomic (ds_add_f32). Plain atomicAdd(float*) is expanded
// by hipcc into a ds_read/ds_cmpst CAS retry loop (denormal-safe path), which
// serializes on LDS latency under contention — the 3.2ms stall of round 1.
__device__ __forceinline__ void lds_add(float* p, float v) {
  unsafeAtomicAdd(p, v);   // lowers to ds_add_f32 on gfx950 (LDS address space)
}

// ---- dual-dtype input load: f32mode ? float : bf16 ----
__device__ __forceinline__ float ld(const void* p, int i, int f32mode) {
  if (f32mode) return ((const float*)p)[i];
  unsigned u = ((const unsigned short*)p)[i];
  return __uint_as_float(u << 16);
}

// Abramowitz & Stegun 7.1.26, |err| <= 1.5e-7.
__device__ __forceinline__ float erf_f(float x) {
  float ax = fabsf(x);
  float t = 1.0f / (1.0f + 0.3275911f * ax);
  float y = t * (0.254829592f +
           t * (-0.284496736f +
           t * (1.421413741f +
           t * (-1.453152027f +
           t * 1.061405429f))));
  y = 1.0f - y * __expf(-ax * ax);
  return copysignf(y, x);
}

// Strip range touched by a record: gaussian window (5s truncation, matches
// the scatter) unioned with the bubble's 2 bilinear rows (f=0 records only).
__device__ __forceinline__ void strip_range(float row, float s, int has_bubble,
                                            int& slo, int& shi) {
  float Rf = 5.0f * s + 0.5f;
  int rlo = max(0, (int)ceilf(row - Rf));
  int rhi = min(HH - 1, (int)floorf(row + Rf));
  slo = 1; shi = 0;                       // empty
  if (rlo <= rhi) { slo = rlo >> SHLOG; shi = rhi >> SHLOG; }
  if (has_bubble) {
    int r0 = (int)floorf(row);
    int rr0 = min(max(r0, 0), HH - 1);
    int rr1 = min(max(r0 + 1, 0), HH - 1);
    int b0 = rr0 >> SHLOG, b1 = rr1 >> SHLOG;
    if (slo > shi) { slo = b0; shi = b1; }
    else { slo = min(slo, b0); shi = max(shi, b1); }
  }
}

// K1: detect dtype, then invert the 8 4x4 transforms (Gauss-Jordan), f32.
__global__ void k_inv(const void* __restrict__ T, float* __restrict__ invT,
                      int* __restrict__ flag) {
  int b = threadIdx.x;
  if (b >= BB) return;
  const float* Tf = (const float*)T;
  int f32mode = (fabsf(Tf[0] - 1.f) < 0.4f &&
                 fabsf(Tf[5] - 1.f) < 0.4f &&
                 fabsf(Tf[10] - 1.f) < 0.4f) ? 1 : 0;
  if (b == 0) *flag = f32mode;

  float a[4][8];
  for (int r = 0; r < 4; ++r)
    for (int c = 0; c < 4; ++c) {
      a[r][c] = ld(T, b * 16 + r * 4 + c, f32mode);
      a[r][4 + c] = (r == c) ? 1.0f : 0.0f;
    }
  for (int k = 0; k < 4; ++k) {
    int p = k; float best = fabsf(a[k][k]);
    for (int i = k + 1; i < 4; ++i) {
      float v = fabsf(a[i][k]);
      if (v > best) { best = v; p = i; }
    }
    if (p != k)
      for (int c = 0; c < 8; ++c) { float tmp = a[k][c]; a[k][c] = a[p][c]; a[p][c] = tmp; }
    float inv = 1.0f / a[k][k];
    for (int c = 0; c < 8; ++c) a[k][c] *= inv;
    for (int i = 0; i < 4; ++i) {
      if (i == k) continue;
      float f = a[i][k];
      for (int c = 0; c < 8; ++c) a[i][c] -= f * a[k][c];
    }
  }
  for (int r = 0; r < 4; ++r)
    for (int c = 0; c < 4; ++c)
      invT[b * 16 + r * 4 + c] = a[r][4 + c];
}

// K2: build per-(b,m) splat records {row, col, scale, weight} and per-block
// per-strip counts (LDS-privatized; one block covers 1024 consecutive records
// of a single batch b, so only SPI strip counters are needed).
__global__ void __launch_bounds__(1024)
k_count(const void* __restrict__ centers, const void* __restrict__ scales,
        const void* __restrict__ weights, const float* __restrict__ invT,
        const int* __restrict__ flag, float4* __restrict__ table,
        int* __restrict__ blkcnt) {
  __shared__ int cnt[SPI];
  int tid = threadIdx.x;
  if (tid < SPI) cnt[tid] = 0;
  __syncthreads();

  int idx = blockIdx.x * blockDim.x + tid;   // exact cover of [0, BB*MM)
  int f32mode = *flag;
  int b = idx >> 14;           // MM = 2^14
  int m = idx & (MM - 1);
  int n = m >> 1;              // FF = 2
  const float* Tb = invT + b * 16;
  float cx = ld(centers, 3 * n, f32mode);
  float cy = ld(centers, 3 * n + 1, f32mode);
  float cz = ld(centers, 3 * n + 2, f32mode);
  float p0 = Tb[0]  * cx + Tb[1]  * cy + Tb[2]  * cz + Tb[3];
  float p1 = Tb[4]  * cx + Tb[5]  * cy + Tb[6]  * cz + Tb[7];
  float p3 = Tb[12] * cx + Tb[13] * cy + Tb[14] * cz + Tb[15];
  float inv = 1.0f / p3;
  float4 rec;
  rec.x = p0 * inv;            // row coordinate (A2P = 1)
  rec.y = p1 * inv;            // col coordinate
  rec.z = ld(scales, m, f32mode);
  rec.w = ld(weights, m, f32mode);
  table[idx] = rec;

  int slo, shi;
  strip_range(rec.x, rec.z, (idx & 1) == 0, slo, shi);
  for (int s2 = slo; s2 <= shi; ++s2) atomicAdd(&cnt[s2], 1);   // int: native
  __syncthreads();
  if (tid < SPI) blkcnt[blockIdx.x * SPI + tid] = cnt[tid];
}

// K3: turn per-block counts into absolute fill bases (in-place) and bin
// offsets. One block, one thread per bin.
__global__ void k_scan(int* __restrict__ blkcnt, int* __restrict__ binoff) {
  __shared__ int tot[BINS];
  int tid = threadIdx.x;               // == bin
  int b = tid >> 6, s2 = tid & (SPI - 1);
  int acc = 0;
  for (int j = 0; j < BLKS_PER_B; ++j) {
    int idx = (b * BLKS_PER_B + j) * SPI + s2;
    int c = blkcnt[idx];
    blkcnt[idx] = acc;                 // local prefix within bin
    acc += c;
  }
  tot[tid] = acc;
  __syncthreads();
  for (int d = 1; d < BINS; d <<= 1) {
    int v = (tid >= d) ? tot[tid - d] : 0;
    __syncthreads();
    tot[tid] += v;
    __syncthreads();
  }
  int off = tot[tid] - acc;            // exclusive prefix over bins
  binoff[tid] = off;
  if (tid == BINS - 1) binoff[BINS] = tot[tid];
  for (int j = 0; j < BLKS_PER_B; ++j)
    blkcnt[(b * BLKS_PER_B + j) * SPI + s2] += off;
}

// K4: scatter record indices into per-bin lists (LDS cursors seeded from the
// per-block bases; order within a bin is irrelevant).
__global__ void __launch_bounds__(1024)
k_fill(const float4* __restrict__ table, const int* __restrict__ blkbase,
       int* __restrict__ list) {
  __shared__ int cur[SPI];
  int tid = threadIdx.x;
  if (tid < SPI) cur[tid] = blkbase[blockIdx.x * SPI + tid];
  __syncthreads();
  int idx = blockIdx.x * blockDim.x + tid;
  float4 rec = table[idx];
  int slo, shi;
  strip_range(rec.x, rec.z, (idx & 1) == 0, slo, shi);
  for (int s2 = slo; s2 <= shi; ++s2) {
    int pos = atomicAdd(&cur[s2], 1);                           // int: native
    list[pos] = idx;
  }
}

// K5: one block per (b,strip) bin. Accumulate all overlapping splats into an
// exclusive LDS strip via native ds_add_f32, then flush straight to the
// output in the detected dtype. 16 waves/block, waves stride the list.
__global__ void __launch_bounds__(1024)
k_gather(const float4* __restrict__ table, const int* __restrict__ list,
         const int* __restrict__ binoff, const void* __restrict__ bwv,
         const int* __restrict__ flag, void* __restrict__ out) {
  __shared__ __align__(16) float tile[SH][WW];   // 16 KB
  int bin = blockIdx.x;
  int b = bin >> 6;
  int strip = bin & (SPI - 1);
  int row0 = strip << SHLOG;
  int tid = threadIdx.x;
  for (int j = tid; j < SH * WW; j += blockDim.x) ((float*)tile)[j] = 0.f;
  __syncthreads();

  int lo = binoff[bin], hi = binoff[bin + 1];
  int lane = tid & 63;
  int wv = tid >> 6;
  int nwv = blockDim.x >> 6;
  int f32mode = *flag;

  for (int p = lo + wv; p < hi; p += nwv) {
    int i = list[p];
    float4 rec = table[i];
    float row = rec.x, col = rec.y, s = rec.z, w = rec.w;

    // ---- bubble point-mass (f=0 records; each pixel owned by its strip) ----
    if ((i & 1) == 0) {
      float r0f = floorf(row), c0f = floorf(col);
      float fr = row - r0f, fc = col - c0f;
      int r0 = (int)r0f, c0 = (int)c0f;
      int rr0 = min(max(r0, 0), HH - 1), rr1 = min(max(r0 + 1, 0), HH - 1);
      int cc0 = min(max(c0, 0), WW - 1), cc1 = min(max(c0 + 1, 0), WW - 1);
      int rsel = (lane < 2) ? rr0 : rr1;
      int csel = (lane & 1) ? cc1 : cc0;
      float wr = (lane < 2) ? (1.f - fr) : fr;
      float wc = (lane & 1) ? fc : (1.f - fc);
      if (lane < 4 && (rsel >> SHLOG) == strip) {
        int n = (i & (MM - 1)) >> 1;
        float bw = ld(bwv, n, f32mode);
        lds_add(&tile[rsel - row0][csel], bw * wr * wc);
      }
    }

    // ---- separable gaussian, rows intersected with this strip ----
    float rs = 0.70710678118f / s;           // 1/(s*sqrt(2))
    float Rf = 5.0f * s + 0.5f;
    int rlo = max(0, (int)ceilf(row - Rf));
    int rhi = min(HH - 1, (int)floorf(row + Rf));
    int clo = max(0, (int)ceilf(col - Rf));
    int chi = min(WW - 1, (int)floorf(col + Rf));
    int srlo = max(rlo, row0);
    int srhi = min(rhi, row0 + SH - 1);
    if (srlo > srhi || clo > chi) continue;
    int nc = chi - clo + 1;
    int nrs = srhi - srlo + 1;
    // column boundary erfs, lane l holds E at x = clo+l-0.5  (nc <= 42)
    float Ew = erf_f(((float)(clo + lane) - 0.5f - col) * rs);
    float pwq = (__shfl_down(Ew, 1) - Ew) * (0.25f * w);
    // row boundary erfs within strip (<= SH+1 = 9 boundaries)
    float Eh = erf_f(((float)(srlo + lane) - 0.5f - row) * rs);
    float Dh = __shfl_down(Eh, 1) - Eh;
#pragma unroll
    for (int k = 0; k < SH; ++k) {
      if (k < nrs) {
        float dh = __shfl(Dh, k);
        if (lane < nc)
          lds_add(&tile[srlo - row0 + k][clo + lane], dh * pwq);
      }
    }
  }
  __syncthreads();

  // ---- exclusive flush: strip -> output (no staging image, no k_final) ----
  size_t pixbase = (size_t)b * HW + (size_t)row0 * WW;
  const float4* t4 = (const float4*)tile;
  if (f32mode) {
    float4* o = (float4*)out + (pixbase >> 2);
    for (int j = tid; j < SH * WW / 4; j += blockDim.x) o[j] = t4[j];
  } else {
    ushort4* o = (ushort4*)out + (pixbase >> 2);
    for (int j = tid; j < SH * WW / 4; j += blockDim.x) {
      float4 v = t4[j];
      __hip_bfloat16 h0 = __float2bfloat16(v.x);
      __hip_bfloat16 h1 = __float2bfloat16(v.y);
      __hip_bfloat16 h2 = __float2bfloat16(v.z);
      __hip_bfloat16 h3 = __float2bfloat16(v.w);
      ushort4 t;
      t.x = *reinterpret_cast<unsigned short*>(&h0);
      t.y = *reinterpret_cast<unsigned short*>(&h1);
      t.z = *reinterpret_cast<unsigned short*>(&h2);
      t.w = *reinterpret_cast<unsigned short*>(&h3);
      o[j] = t;
    }
  }
}

extern "C" void kernel_launch(void* const* d_in, const int* in_sizes, int n_in,
                              void* d_out, int out_size, void* d_ws, size_t ws_size,
                              hipStream_t stream) {
  const void* T       = d_in[0];   // (B,4,4)
  const void* centers = d_in[1];   // (N,3)
  const void* scales  = d_in[2];   // (N,F)
  const void* weights = d_in[3];   // (N,F)
  const void* bubble  = d_in[4];   // (N,)

  char* ws = (char*)d_ws;
  size_t off = 0;
  float4* table = (float4*)(ws + off); off += (size_t)BB * MM * 16;       // 2 MB
  int*    list  = (int*)(ws + off);    off += (size_t)LIST_CAP * 4;       // 4 MB
  int*    blkcnt= (int*)(ws + off);    off += (size_t)NBLK * SPI * 4;     // 32 KB
  int*    binoff= (int*)(ws + off);    off += (size_t)(BINS + 1) * 4 + 12;
  off = (off + 15) & ~(size_t)15;
  float*  invT  = (float*)(ws + off);  off += (size_t)BB * 16 * 4;        // 512 B
  int*    flag  = (int*)(ws + off);

  k_inv  <<<1,    64,   0, stream>>>(T, invT, flag);
  k_count<<<NBLK, 1024, 0, stream>>>(centers, scales, weights, invT, flag, table, blkcnt);
  k_scan <<<1,    BINS, 0, stream>>>(blkcnt, binoff);
  k_fill <<<NBLK, 1024, 0, stream>>>(table, blkcnt, list);
  k_gather<<<BINS,1024, 0, stream>>>(table, list, binoff, bubble, flag, d_out);
}

// Round 3
// 3007.178 us; speedup vs baseline: 1.0915x; 1.0904x over previous
//
#include <hip/hip_runtime.h>
#include <hip/hip_bf16.h>

// Problem constants (from reference)
#define HH 512
#define WW 512
#define NN 8192
#define FF 2
#define BB 8
#define MM (NN * FF)      // 16384 splats per batch
#define HW (HH * WW)      // 262144 pixels per batch image

// Strip binning: exclusive 8-row strips, one block owns one strip in LDS.
#define SHLOG 3
#define SH 8                  // strip height (rows)
#define SPI (HH / SH)         // 64 strips per image
#define BINS (BB * SPI)       // 512 bins
#define NBLK 128              // blocks for count/fill (1024 thr each -> exact cover)
#define BLKS_PER_B (NBLK / BB)   // 16
#define LIST_CAP (BB * MM * 8)   // max 7 strips/record (Rf<=20.5 -> <=42 rows)

// Native fp32 LDS atomic (ds_add_f32), fire-and-forget.
__device__ __forceinline__ void lds_add(float* p, float v) {
  unsafeAtomicAdd(p, v);
}

// Cross-lane broadcast via v_readlane (VALU/SALU path — NO ds_bpermute, so it
// never waits behind the ds_add_f32 queue in lgkmcnt). Lane index must be a
// compile-time constant here (loop fully unrolled).
__device__ __forceinline__ float readlane_f(float v, int l) {
  return __uint_as_float(__builtin_amdgcn_readlane(__float_as_uint(v), l));
}

// ---- dual-dtype input load: f32mode ? float : bf16 ----
__device__ __forceinline__ float ld(const void* p, int i, int f32mode) {
  if (f32mode) return ((const float*)p)[i];
  unsigned u = ((const unsigned short*)p)[i];
  return __uint_as_float(u << 16);
}

// Abramowitz & Stegun 7.1.26, |err| <= 1.5e-7.
__device__ __forceinline__ float erf_f(float x) {
  float ax = fabsf(x);
  float t = 1.0f / (1.0f + 0.3275911f * ax);
  float y = t * (0.254829592f +
           t * (-0.284496736f +
           t * (1.421413741f +
           t * (-1.453152027f +
           t * 1.061405429f))));
  y = 1.0f - y * __expf(-ax * ax);
  return copysignf(y, x);
}

// Strip range touched by a record: gaussian window (5s truncation, matches
// the scatter) unioned with the bubble's 2 bilinear rows (f=0 records only).
__device__ __forceinline__ void strip_range(float row, float s, int has_bubble,
                                            int& slo, int& shi) {
  float Rf = 5.0f * s + 0.5f;
  int rlo = max(0, (int)ceilf(row - Rf));
  int rhi = min(HH - 1, (int)floorf(row + Rf));
  slo = 1; shi = 0;                       // empty
  if (rlo <= rhi) { slo = rlo >> SHLOG; shi = rhi >> SHLOG; }
  if (has_bubble) {
    int r0 = (int)floorf(row);
    int rr0 = min(max(r0, 0), HH - 1);
    int rr1 = min(max(r0 + 1, 0), HH - 1);
    int b0 = rr0 >> SHLOG, b1 = rr1 >> SHLOG;
    if (slo > shi) { slo = b0; shi = b1; }
    else { slo = min(slo, b0); shi = max(shi, b1); }
  }
}

// K1: detect dtype, then invert the 8 4x4 transforms (Gauss-Jordan), f32.
__global__ void k_inv(const void* __restrict__ T, float* __restrict__ invT,
                      int* __restrict__ flag) {
  int b = threadIdx.x;
  if (b >= BB) return;
  const float* Tf = (const float*)T;
  int f32mode = (fabsf(Tf[0] - 1.f) < 0.4f &&
                 fabsf(Tf[5] - 1.f) < 0.4f &&
                 fabsf(Tf[10] - 1.f) < 0.4f) ? 1 : 0;
  if (b == 0) *flag = f32mode;

  float a[4][8];
  for (int r = 0; r < 4; ++r)
    for (int c = 0; c < 4; ++c) {
      a[r][c] = ld(T, b * 16 + r * 4 + c, f32mode);
      a[r][4 + c] = (r == c) ? 1.0f : 0.0f;
    }
  for (int k = 0; k < 4; ++k) {
    int p = k; float best = fabsf(a[k][k]);
    for (int i = k + 1; i < 4; ++i) {
      float v = fabsf(a[i][k]);
      if (v > best) { best = v; p = i; }
    }
    if (p != k)
      for (int c = 0; c < 8; ++c) { float tmp = a[k][c]; a[k][c] = a[p][c]; a[p][c] = tmp; }
    float inv = 1.0f / a[k][k];
    for (int c = 0; c < 8; ++c) a[k][c] *= inv;
    for (int i = 0; i < 4; ++i) {
      if (i == k) continue;
      float f = a[i][k];
      for (int c = 0; c < 8; ++c) a[i][c] -= f * a[k][c];
    }
  }
  for (int r = 0; r < 4; ++r)
    for (int c = 0; c < 4; ++c)
      invT[b * 16 + r * 4 + c] = a[r][4 + c];
}

// K2: build per-(b,m) splat records {row, col, scale, weight} and per-block
// per-strip counts (LDS-privatized; one block covers 1024 consecutive records
// of a single batch b, so only SPI strip counters are needed).
__global__ void __launch_bounds__(1024)
k_count(const void* __restrict__ centers, const void* __restrict__ scales,
        const void* __restrict__ weights, const float* __restrict__ invT,
        const int* __restrict__ flag, float4* __restrict__ table,
        int* __restrict__ blkcnt) {
  __shared__ int cnt[SPI];
  int tid = threadIdx.x;
  if (tid < SPI) cnt[tid] = 0;
  __syncthreads();

  int idx = blockIdx.x * blockDim.x + tid;   // exact cover of [0, BB*MM)
  int f32mode = *flag;
  int b = idx >> 14;           // MM = 2^14
  int m = idx & (MM - 1);
  int n = m >> 1;              // FF = 2
  const float* Tb = invT + b * 16;
  float cx = ld(centers, 3 * n, f32mode);
  float cy = ld(centers, 3 * n + 1, f32mode);
  float cz = ld(centers, 3 * n + 2, f32mode);
  float p0 = Tb[0]  * cx + Tb[1]  * cy + Tb[2]  * cz + Tb[3];
  float p1 = Tb[4]  * cx + Tb[5]  * cy + Tb[6]  * cz + Tb[7];
  float p3 = Tb[12] * cx + Tb[13] * cy + Tb[14] * cz + Tb[15];
  float inv = 1.0f / p3;
  float4 rec;
  rec.x = p0 * inv;            // row coordinate (A2P = 1)
  rec.y = p1 * inv;            // col coordinate
  rec.z = ld(scales, m, f32mode);
  rec.w = ld(weights, m, f32mode);
  table[idx] = rec;

  int slo, shi;
  strip_range(rec.x, rec.z, (idx & 1) == 0, slo, shi);
  for (int s2 = slo; s2 <= shi; ++s2) atomicAdd(&cnt[s2], 1);   // int: native
  __syncthreads();
  if (tid < SPI) blkcnt[blockIdx.x * SPI + tid] = cnt[tid];
}

// K3: turn per-block counts into absolute fill bases (in-place) and bin
// offsets. One block, one thread per bin.
__global__ void k_scan(int* __restrict__ blkcnt, int* __restrict__ binoff) {
  __shared__ int tot[BINS];
  int tid = threadIdx.x;               // == bin
  int b = tid >> 6, s2 = tid & (SPI - 1);
  int acc = 0;
  for (int j = 0; j < BLKS_PER_B; ++j) {
    int idx = (b * BLKS_PER_B + j) * SPI + s2;
    int c = blkcnt[idx];
    blkcnt[idx] = acc;                 // local prefix within bin
    acc += c;
  }
  tot[tid] = acc;
  __syncthreads();
  for (int d = 1; d < BINS; d <<= 1) {
    int v = (tid >= d) ? tot[tid - d] : 0;
    __syncthreads();
    tot[tid] += v;
    __syncthreads();
  }
  int off = tot[tid] - acc;            // exclusive prefix over bins
  binoff[tid] = off;
  if (tid == BINS - 1) binoff[BINS] = tot[tid];
  for (int j = 0; j < BLKS_PER_B; ++j)
    blkcnt[(b * BLKS_PER_B + j) * SPI + s2] += off;
}

// K4: scatter record indices into per-bin lists (LDS cursors seeded from the
// per-block bases; order within a bin is irrelevant).
__global__ void __launch_bounds__(1024)
k_fill(const float4* __restrict__ table, const int* __restrict__ blkbase,
       int* __restrict__ list) {
  __shared__ int cur[SPI];
  int tid = threadIdx.x;
  if (tid < SPI) cur[tid] = blkbase[blockIdx.x * SPI + tid];
  __syncthreads();
  int idx = blockIdx.x * blockDim.x + tid;
  float4 rec = table[idx];
  int slo, shi;
  strip_range(rec.x, rec.z, (idx & 1) == 0, slo, shi);
  for (int s2 = slo; s2 <= shi; ++s2) {
    int pos = atomicAdd(&cur[s2], 1);                           // int: native
    list[pos] = idx;
  }
}

// K5: one block per (b,strip) bin. Accumulate all overlapping splats into an
// exclusive LDS strip via ds_add_f32, then flush straight to the output.
// Inner loop is SHUFFLE-FREE: columns get per-lane 2-erf profiles, rows get
// a lane-computed boundary vector broadcast via v_readlane (no ds_bpermute,
// so nothing waits behind the outstanding ds_add queue in lgkmcnt).
// list/table loads are software-prefetched one iteration ahead.
__global__ void __launch_bounds__(1024)
k_gather(const float4* __restrict__ table, const int* __restrict__ list,
         const int* __restrict__ binoff, const void* __restrict__ bwv,
         const int* __restrict__ flag, void* __restrict__ out) {
  __shared__ __align__(16) float tile[SH][WW];   // 16 KB
  int bin = blockIdx.x;
  int b = bin >> 6;
  int strip = bin & (SPI - 1);
  int row0 = strip << SHLOG;
  int tid = threadIdx.x;
  for (int j = tid; j < SH * WW; j += blockDim.x) ((float*)tile)[j] = 0.f;
  __syncthreads();

  int lo = binoff[bin], hi = binoff[bin + 1];
  int lane = tid & 63;
  int wv = tid >> 6;
  int nwv = blockDim.x >> 6;
  int f32mode = *flag;

  int p = lo + wv;
  int icur = 0;
  float4 rec = make_float4(0.f, 0.f, 0.f, 0.f);
  if (p < hi) { icur = list[p]; rec = table[icur]; }

  while (p < hi) {
    // ---- prefetch next entry (hides list->table L2 chain under the math) --
    int pn = p + nwv;
    int inext = 0;
    float4 recn = rec;
    if (pn < hi) { inext = list[pn]; recn = table[inext]; }

    float row = rec.x, col = rec.y, s = rec.z, w = rec.w;

    // ---- bubble point-mass (f=0 records; each pixel owned by its strip) ----
    if ((icur & 1) == 0) {
      float r0f = floorf(row), c0f = floorf(col);
      float fr = row - r0f, fc = col - c0f;
      int r0 = (int)r0f, c0 = (int)c0f;
      int rr0 = min(max(r0, 0), HH - 1), rr1 = min(max(r0 + 1, 0), HH - 1);
      int cc0 = min(max(c0, 0), WW - 1), cc1 = min(max(c0 + 1, 0), WW - 1);
      int rsel = (lane < 2) ? rr0 : rr1;
      int csel = (lane & 1) ? cc1 : cc0;
      float wr = (lane < 2) ? (1.f - fr) : fr;
      float wc = (lane & 1) ? fc : (1.f - fc);
      if (lane < 4 && (rsel >> SHLOG) == strip) {
        int n = (icur & (MM - 1)) >> 1;
        float bw = ld(bwv, n, f32mode);
        lds_add(&tile[rsel - row0][csel], bw * wr * wc);
      }
    }

    // ---- separable gaussian, rows intersected with this strip ----
    float rs = 0.70710678118f / s;           // 1/(s*sqrt(2))
    float Rf = 5.0f * s + 0.5f;
    int rlo = max(0, (int)ceilf(row - Rf));
    int rhi = min(HH - 1, (int)floorf(row + Rf));
    int clo = max(0, (int)ceilf(col - Rf));
    int chi = min(WW - 1, (int)floorf(col + Rf));
    int srlo = max(rlo, row0);
    int srhi = min(rhi, row0 + SH - 1);
    if (srlo <= srhi && clo <= chi) {
      int nc = chi - clo + 1;
      int nrs = srhi - srlo + 1;
      // per-lane column profile: both boundary erfs locally (no shfl)
      float xlo = ((float)(clo + lane) - 0.5f - col) * rs;
      float Elo = erf_f(xlo);
      float Ehi = erf_f(xlo + rs);           // (c+0.5) boundary
      float pw  = (Ehi - Elo) * (0.25f * w);
      // row boundaries: lane k holds E(srlo+k-0.5); broadcast via readlane
      float Eh = erf_f(((float)(srlo + lane) - 0.5f - row) * rs);
      float* tbase = &tile[srlo - row0][0];
#pragma unroll
      for (int k = 0; k < SH; ++k) {
        if (k < nrs) {
          float dh = readlane_f(Eh, k + 1) - readlane_f(Eh, k);
          if (lane < nc)
            lds_add(tbase + (k << 9) + clo + lane, dh * pw);
        }
      }
    }

    p = pn; icur = inext; rec = recn;
  }
  __syncthreads();

  // ---- exclusive flush: strip -> output (no staging image, no k_final) ----
  size_t pixbase = (size_t)b * HW + (size_t)row0 * WW;
  const float4* t4 = (const float4*)tile;
  if (f32mode) {
    float4* o = (float4*)out + (pixbase >> 2);
    for (int j = tid; j < SH * WW / 4; j += blockDim.x) o[j] = t4[j];
  } else {
    ushort4* o = (ushort4*)out + (pixbase >> 2);
    for (int j = tid; j < SH * WW / 4; j += blockDim.x) {
      float4 v = t4[j];
      __hip_bfloat16 h0 = __float2bfloat16(v.x);
      __hip_bfloat16 h1 = __float2bfloat16(v.y);
      __hip_bfloat16 h2 = __float2bfloat16(v.z);
      __hip_bfloat16 h3 = __float2bfloat16(v.w);
      ushort4 t;
      t.x = *reinterpret_cast<unsigned short*>(&h0);
      t.y = *reinterpret_cast<unsigned short*>(&h1);
      t.z = *reinterpret_cast<unsigned short*>(&h2);
      t.w = *reinterpret_cast<unsigned short*>(&h3);
      o[j] = t;
    }
  }
}

extern "C" void kernel_launch(void* const* d_in, const int* in_sizes, int n_in,
                              void* d_out, int out_size, void* d_ws, size_t ws_size,
                              hipStream_t stream) {
  const void* T       = d_in[0];   // (B,4,4)
  const void* centers = d_in[1];   // (N,3)
  const void* scales  = d_in[2];   // (N,F)
  const void* weights = d_in[3];   // (N,F)
  const void* bubble  = d_in[4];   // (N,)

  char* ws = (char*)d_ws;
  size_t off = 0;
  float4* table = (float4*)(ws + off); off += (size_t)BB * MM * 16;       // 2 MB
  int*    list  = (int*)(ws + off);    off += (size_t)LIST_CAP * 4;       // 4 MB
  int*    blkcnt= (int*)(ws + off);    off += (size_t)NBLK * SPI * 4;     // 32 KB
  int*    binoff= (int*)(ws + off);    off += (size_t)(BINS + 1) * 4 + 12;
  off = (off + 15) & ~(size_t)15;
  float*  invT  = (float*)(ws + off);  off += (size_t)BB * 16 * 4;        // 512 B
  int*    flag  = (int*)(ws + off);

  k_inv  <<<1,    64,   0, stream>>>(T, invT, flag);
  k_count<<<NBLK, 1024, 0, stream>>>(centers, scales, weights, invT, flag, table, blkcnt);
  k_scan <<<1,    BINS, 0, stream>>>(blkcnt, binoff);
  k_fill <<<NBLK, 1024, 0, stream>>>(table, blkcnt, list);
  k_gather<<<BINS,1024, 0, stream>>>(table, list, binoff, bubble, flag, d_out);
}